// Round 9
// baseline (153.069 us; speedup 1.0000x reference)
//
#include <hip/hip_runtime.h>

typedef unsigned short u16;
typedef float f32x4 __attribute__((ext_vector_type(4)));
typedef short short8 __attribute__((ext_vector_type(8)));
typedef unsigned int uint2v __attribute__((ext_vector_type(2)));

#define B_ 32
#define N_ 1024
#define D_ 512
#define K_ 64
#define KG_ 80
#define MT_ 32768          // total rows B*N

__device__ __forceinline__ u16 f2bf(float f) {
  union { float f; unsigned u; } x; x.f = f;
  unsigned u = x.u;
  u += 0x7FFFu + ((u >> 16) & 1u);          // RNE, finite data
  return (u16)(u >> 16);
}
__device__ __forceinline__ void split2(float v, u16& h, u16& l) {
  union { float f; unsigned u; } x; x.f = v;
  unsigned hu = x.u & 0xFFFF0000u;          // truncate -> hi
  h = (u16)(hu >> 16);
  union { unsigned u; float f; } hf; hf.u = hu;
  l = f2bf(v - hf.f);                       // exact remainder, rne -> lo
}

// ---------------------------------------------------------------------------
// K0: BN fold; zero accumulators; pack clusters into MFMA A-fragments (hi/lo).
// cpk layout: [kk=16][h=2][cf=5][lane=64][j=8] u16
//   element = clusters[d=kk*32+(lane>>4)*8+j][col=cf*16+(lane&15)]
// ---------------------------------------------------------------------------
__global__ void k_prep(const float* __restrict__ clusters,
                       const float* __restrict__ bn_w, const float* __restrict__ bn_b,
                       const float* __restrict__ bn_m, const float* __restrict__ bn_v,
                       u16* __restrict__ cpk, float* __restrict__ bn_sc,
                       float* __restrict__ bn_sh,
                       float* __restrict__ asum, float* __restrict__ ssq) {
  int t = blockIdx.x * 256 + threadIdx.x;
  if (t < KG_) {
    float sc = bn_w[t] * rsqrtf(bn_v[t] + 1e-5f);
    bn_sc[t] = sc;
    bn_sh[t] = bn_b[t] - bn_m[t] * sc;
  }
  if (t < B_ * K_) asum[t] = 0.0f;
  if (t < B_) ssq[t] = 0.0f;
  if (t < 5120) {                            // (kk*5+cf)*64 + lane
    int grp = t >> 6;
    int kk = grp / 5, cf = grp % 5;
    int lane = t & 63;
    int col = cf * 16 + (lane & 15);
#pragma unroll
    for (int j = 0; j < 8; j++) {
      int d = kk * 32 + ((lane >> 4) << 3) + j;
      float v = clusters[(size_t)d * 80 + col];
      u16 h, l; split2(v, h, l);
      cpk[(size_t)kk * 5120 + ((0 * 5 + cf) * 64 + lane) * 8 + j] = h;
      cpk[(size_t)kk * 5120 + ((1 * 5 + cf) * 64 + lane) * 8 + j] = l;
    }
  }
}

// ---------------------------------------------------------------------------
// K1 (MFMA, logits^T): C[c=80][n], A = clusters frags (cpk, L2-hot),
// B = x rows natural layout. K-split: 4 waves = 2 n-groups x 2 K-halves.
// ALL 16 x-loads issued upfront (256B/thread in flight -> HBM-rate stream,
// latency exposed once). No barriers in the loop. LDS merge of K-halves,
// in-wave softmax, aT bounce -> coalesced stores, asum atomics.
// ---------------------------------------------------------------------------
__global__ __launch_bounds__(256, 3) void k_assign(
    const float* __restrict__ x, const u16* __restrict__ cpk,
    const float* __restrict__ bn_sc, const float* __restrict__ bn_sh,
    u16* __restrict__ aT, float* __restrict__ asum_g) {
  __shared__ f32x4 mrg[2][5][64];   // [g][cf][lane] K-half-1 partials
  __shared__ u16 aTs[64][40];       // [c][n_local 0..31]

  int t = threadIdx.x;
  int lane = t & 63;
  int w = t >> 6;
  int g = w & 1;                    // n-group (16 n each)
  int h = w >> 1;                   // K-half
  int l15 = lane & 15, lhi = lane >> 4;
  int n0 = blockIdx.x * 32;
  int b = blockIdx.x >> 5;          // 32 blocks per batch
  int nw = n0 + g * 16 + l15;
  int kk0 = h * 8;

  const float* xrow = x + (size_t)nw * 512 + lhi * 8;

  f32x4 acc[5];
#pragma unroll
  for (int cf = 0; cf < 5; cf++) acc[cf] = (f32x4)0.0f;

  // issue the wave's ENTIRE K-half of x upfront (16 x dwordx4)
  f32x4 xq[8][2];
#pragma unroll
  for (int p = 0; p < 8; p++) {
    xq[p][0] = *(const f32x4*)(xrow + (kk0 + p) * 32);
    xq[p][1] = *(const f32x4*)(xrow + (kk0 + p) * 32 + 4);
  }

#pragma unroll
  for (int s = 0; s < 8; s++) {
    int kk = kk0 + s;
    const short8* ap = (const short8*)(cpk + (size_t)kk * 5120);
    short8 Ah[5], Al[5];
#pragma unroll
    for (int cf = 0; cf < 5; cf++) {
      Ah[cf] = ap[cf * 64 + lane];
      Al[cf] = ap[(5 + cf) * 64 + lane];
    }
    f32x4 v0 = xq[s][0], v1 = xq[s][1];
    short8 bh, bl;
#pragma unroll
    for (int j = 0; j < 4; j++) {
      u16 hh, ll;
      split2(v0[j], hh, ll); bh[j] = hh;     bl[j] = ll;
      split2(v1[j], hh, ll); bh[j + 4] = hh; bl[j + 4] = ll;
    }
#pragma unroll
    for (int cf = 0; cf < 5; cf++) {
      acc[cf] = __builtin_amdgcn_mfma_f32_16x16x32_bf16(Ah[cf], bh, acc[cf], 0, 0, 0);
      acc[cf] = __builtin_amdgcn_mfma_f32_16x16x32_bf16(Ah[cf], bl, acc[cf], 0, 0, 0);
      acc[cf] = __builtin_amdgcn_mfma_f32_16x16x32_bf16(Al[cf], bh, acc[cf], 0, 0, 0);
    }
  }

  if (h == 1) {
#pragma unroll
    for (int cf = 0; cf < 5; cf++) mrg[g][cf][lane] = acc[cf];
  }
  __syncthreads();

  if (h == 0) {
#pragma unroll
    for (int cf = 0; cf < 5; cf++) acc[cf] += mrg[g][cf][lane];

    // BN + softmax: lane's n has 20 c locally; full 80 via shfl(16,32)
    f32x4 sc4[5], sh4[5];
#pragma unroll
    for (int cf = 0; cf < 5; cf++) {
      sc4[cf] = *(const f32x4*)&bn_sc[cf * 16 + lhi * 4];
      sh4[cf] = *(const f32x4*)&bn_sh[cf * 16 + lhi * 4];
    }
    float lv[5][4], mx = -3.0e38f;
#pragma unroll
    for (int cf = 0; cf < 5; cf++)
#pragma unroll
      for (int r = 0; r < 4; r++) {
        lv[cf][r] = fmaf(acc[cf][r], sc4[cf][r], sh4[cf][r]);
        mx = fmaxf(mx, lv[cf][r]);
      }
    float M = mx;
    M = fmaxf(M, __shfl_xor(M, 16)); M = fmaxf(M, __shfl_xor(M, 32));
    float s = 0.0f;
#pragma unroll
    for (int cf = 0; cf < 5; cf++)
#pragma unroll
      for (int r = 0; r < 4; r++) { lv[cf][r] = __expf(lv[cf][r] - M); s += lv[cf][r]; }
    s += __shfl_xor(s, 16); s += __shfl_xor(s, 32);
    float inv = 1.0f / s;

#pragma unroll
    for (int cf = 0; cf < 4; cf++) {          // c 64..79 dropped
#pragma unroll
      for (int r = 0; r < 4; r++) {
        float a = lv[cf][r] * inv;
        aTs[cf * 16 + lhi * 4 + r][g * 16 + l15] = f2bf(a);
        float ps = a;                          // reduce over 16 n (l15 bits)
        ps += __shfl_xor(ps, 1); ps += __shfl_xor(ps, 2);
        ps += __shfl_xor(ps, 4); ps += __shfl_xor(ps, 8);
        if (l15 == 0) atomicAdd(&asum_g[b * 64 + cf * 16 + lhi * 4 + r], ps);
      }
    }
  }
  __syncthreads();
  // aT writeout: 64 c rows x 32 n, 4 threads/row x 16B
  {
    int k = t >> 2, seg = t & 3;
    short8 uu = *(const short8*)&aTs[k][seg * 8];
    *(short8*)(aT + (size_t)k * MT_ + n0 + seg * 8) = uu;
  }
}

// ---------------------------------------------------------------------------
// K2 (MFMA): vlad[b][d][k] = sum_n x[n][d]*aT[k][n] - asum*c2.
// 1024 blocks = (dt:32 of 16 d) x (b:32); id%8=b%8 pins batch to one XCD.
// x staged as LDS [128 n][16 d] bf16 rows (ONE b128 write/thread/chunk);
// A-frags read via ds_read_b64_tr_b16 hardware transpose (2/frag).
// 4 waves = 4 n-slices (K-split), B-frags 16B from aT (L2-hot);
// LDS merge of the 4 partials; fused -asum*c2 + ssq epilogue.
// ---------------------------------------------------------------------------
__global__ __launch_bounds__(256, 4) void k_vlad(
    const float* __restrict__ x, const u16* __restrict__ aT,
    const float* __restrict__ asum_g, const float* __restrict__ c2,
    float* __restrict__ vlad, float* __restrict__ ssq) {
  __shared__ u16 xs[2][128][16];    // [buf][n][d] bf16, 32B rows
  __shared__ f32x4 mrg[4][4][64];   // [wave][kf][lane]
  __shared__ float wred[4];

  int t = threadIdx.x;
  int lane = t & 63;
  int w = t >> 6;                   // n-slice of the chunk
  int id = blockIdx.x;
  int b = id & 31;
  int d0 = (id >> 5) * 16;
  int l15 = lane & 15, lhi = lane >> 4;

  const float* xb = x + (size_t)b * 524288 + d0;
  const u16* abase = aT + b * 1024 + (size_t)l15 * MT_ + w * 32 + lhi * 8;

  int nl = t >> 1;                  // 0..127 chunk-local n
  int dh = (t & 1) * 8;             // d offset 0/8
  unsigned xsb = (unsigned)(size_t)&xs[0][0][0];
  // tr-read lane addr: 128B tile base (rows w*32+lhi*8) + column l15*8
  unsigned trb = xsb + (unsigned)((w * 32 + lhi * 8) * 32 + l15 * 8);

  f32x4 acc[4];
#pragma unroll
  for (int kf = 0; kf < 4; kf++) acc[kf] = (f32x4)0.0f;

  // prologue: stage chunk 0
  {
    f32x4 s0 = *(const f32x4*)&xb[(size_t)nl * 512 + dh];
    f32x4 s1 = *(const f32x4*)&xb[(size_t)nl * 512 + dh + 4];
    short8 pk;
#pragma unroll
    for (int i = 0; i < 4; i++) { pk[i] = (short)f2bf(s0[i]); pk[i + 4] = (short)f2bf(s1[i]); }
    *(short8*)&xs[0][nl][dh] = pk;
  }
  __syncthreads();

#pragma unroll 2
  for (int c = 0; c < 8; c++) {
    int cur = c & 1;
    f32x4 p0, p1;
    if (c < 7) {                    // next chunk's globals, issued early
      p0 = *(const f32x4*)&xb[(size_t)((c + 1) * 128 + nl) * 512 + dh];
      p1 = *(const f32x4*)&xb[(size_t)((c + 1) * 128 + nl) * 512 + dh + 4];
    }
    short8 Bf[4];
#pragma unroll
    for (int kf = 0; kf < 4; kf++)
      Bf[kf] = *(const short8*)(abase + (size_t)kf * 16 * MT_ + c * 128);

    // A-frag: hardware transpose read of this wave's 32-n slice
    uint2v ra, rb;
    unsigned a0 = trb + (unsigned)(cur * 4096);
    asm volatile("ds_read_b64_tr_b16 %0, %1" : "=v"(ra) : "v"(a0));
    asm volatile("ds_read_b64_tr_b16 %0, %1 offset:128" : "=v"(rb) : "v"(a0));
    asm volatile("s_waitcnt lgkmcnt(0)");
    __builtin_amdgcn_sched_barrier(0);
    union { uint2v u[2]; short8 s; } tp;
    tp.u[0] = ra; tp.u[1] = rb;
    short8 Af = tp.s;

#pragma unroll
    for (int kf = 0; kf < 4; kf++)
      acc[kf] = __builtin_amdgcn_mfma_f32_16x16x32_bf16(Af, Bf[kf], acc[kf], 0, 0, 0);

    if (c < 7) {                    // stage next chunk into the other buffer
      short8 pk;
#pragma unroll
      for (int i = 0; i < 4; i++) { pk[i] = (short)f2bf(p0[i]); pk[i + 4] = (short)f2bf(p1[i]); }
      *(short8*)&xs[cur ^ 1][nl][dh] = pk;
    }
    __syncthreads();
  }

  // merge the 4 n-slice partials; wave w finishes k-frag w
#pragma unroll
  for (int kf = 0; kf < 4; kf++) mrg[w][kf][lane] = acc[kf];
  __syncthreads();

  f32x4 vs = mrg[0][w][lane] + mrg[1][w][lane] + mrg[2][w][lane] + mrg[3][w][lane];
  int k = w * 16 + l15;
  float av = asum_g[b * 64 + k];
  float psq = 0.0f;
#pragma unroll
  for (int r = 0; r < 4; r++) {
    int d = d0 + lhi * 4 + r;
    float val = vs[r] - av * c2[(size_t)d * 64 + k];
    vlad[(size_t)b * 32768 + (size_t)d * 64 + k] = val;
    psq += val * val;
  }
  psq += __shfl_xor(psq, 1);  psq += __shfl_xor(psq, 2);
  psq += __shfl_xor(psq, 4);  psq += __shfl_xor(psq, 8);
  psq += __shfl_xor(psq, 16); psq += __shfl_xor(psq, 32);
  if (lane == 0) wred[w] = psq;
  __syncthreads();
  if (t == 0) atomicAdd(&ssq[b], wred[0] + wred[1] + wred[2] + wred[3]);
}

// ---------------------------------------------------------------------------
// K3: out = vlad * scale[b]  (vlad already in output layout [b][d][k])
// ---------------------------------------------------------------------------
__global__ __launch_bounds__(256) void k_out(const float* __restrict__ vlad,
                                             const float* __restrict__ ssq,
                                             float* __restrict__ out) {
  int bb = blockIdx.x >> 5;         // 32 blocks per batch
  float S = ssq[bb];
  float n1 = sqrtf(S + 1e-12f);
  float n2 = sqrtf(S / (S + 1e-12f) + 1e-12f);
  float s = 1.0f / (n1 * n2);
  size_t idx = ((size_t)blockIdx.x * 256 + threadIdx.x) * 4;
  f32x4 v = *(const f32x4*)&vlad[idx];
  f32x4 o;
#pragma unroll
  for (int j = 0; j < 4; j++) o[j] = v[j] * s;
  *(f32x4*)&out[idx] = o;
}

extern "C" void kernel_launch(void* const* d_in, const int* in_sizes, int n_in,
                              void* d_out, int out_size, void* d_ws, size_t ws_size,
                              hipStream_t stream) {
  const float* x        = (const float*)d_in[0];
  const float* clusters = (const float*)d_in[1];
  const float* clusters2= (const float*)d_in[2];
  const float* bn_w     = (const float*)d_in[3];
  const float* bn_b     = (const float*)d_in[4];
  const float* bn_m     = (const float*)d_in[5];
  const float* bn_v     = (const float*)d_in[6];
  float* out = (float*)d_out;

  char* ws = (char*)d_ws;
  u16*   aT    = (u16*)ws;                              // 64*32768 bf16 = 4 MB
  float* vlad  = (float*)(ws + (size_t)4 * 1048576);    // 4 MB
  u16*   cpk   = (u16*)(ws + (size_t)8 * 1048576);      // 160 KB
  float* bn_sc = (float*)(ws + (size_t)8 * 1048576 + 262144);
  float* bn_sh = bn_sc + KG_;
  float* asum  = bn_sh + KG_;                           // 2048 f32
  float* ssq   = asum + B_ * K_;                        // 32 f32

  k_prep<<<20, 256, 0, stream>>>(clusters, bn_w, bn_b, bn_m, bn_v,
                                 cpk, bn_sc, bn_sh, asum, ssq);
  k_assign<<<1024, 256, 0, stream>>>(x, cpk, bn_sc, bn_sh, aT, asum);
  k_vlad<<<1024, 256, 0, stream>>>(x, aT, asum, clusters2, vlad, ssq);
  k_out<<<1024, 256, 0, stream>>>(vlad, ssq, out);
}